// Round 5
// baseline (640.912 us; speedup 1.0000x reference)
//
#include <hip/hip_runtime.h>
#include <math.h>
#include <stdint.h>

#define NE 8
#define ED 1024
#define FD 2048
#define NTOK 2048
#define BM 128
#define BN 128
#define BK 64

typedef unsigned short u16;
typedef unsigned int u32;
typedef __attribute__((ext_vector_type(4))) float f32x4;
typedef __attribute__((ext_vector_type(8))) short s16x8;
typedef __attribute__((ext_vector_type(4))) unsigned int u32v4;

// ---------------- helpers ----------------

__device__ __forceinline__ u16 f2bf(float f) {
    u32 u = __builtin_bit_cast(u32, f);
    u32 r = u + 0x7fffu + ((u >> 16) & 1u);   // RNE
    return (u16)(r >> 16);
}

__device__ __forceinline__ u32 pk2(float a, float b) {
    return (u32)f2bf(a) | ((u32)f2bf(b) << 16);
}

typedef __attribute__((address_space(1))) const void gvoid_t;
typedef __attribute__((address_space(3))) void lvoid_t;

__device__ __forceinline__ void gload16(const void* g, void* l) {
    // async global->LDS, 16B per lane; LDS dest = uniform base + lane*16
    __builtin_amdgcn_global_load_lds((gvoid_t*)g, (lvoid_t*)l, 16, 0, 0);
}

// LDS B-tile layout (same as the old weight-image format, now built in-kernel):
// [64 k][128 rc] tile; 16-B word index = g*128 + rc (g = k-oct 0..7), word =
// 8 consecutive k as bf16. MFMA B-fragment read = word (g4, rc) -> bank slot
// rc&7, balanced. Weights are converted f32->bf16 during reg-staging (no
// separate conversion pass, no weight images in HBM).

// workspace layout (bytes)
#define WS_CNT 0u
#define WS_OFF 64u
#define WS_TOK 256u
#define WS_WT  65792u
#define WS_XB  131328u
#define WS_ACT 4325632u
#define WS_NEED 25297152u

__global__ void k_scan(const int* __restrict__ cnt, int* __restrict__ off) {
    if (threadIdx.x == 0 && blockIdx.x == 0) {
        int a = 0;
#pragma unroll
        for (int e = 0; e < NE; e++) { off[e] = a; a += (cnt[e] + 127) & ~127; }
        off[NE] = a;
    }
}

// ---------------- fused prep: router + x->bf16 ----------------
// blocks [0,512): router (one wave per token); [512,2560): cvtx

__global__ __launch_bounds__(256) void k_prep(
        const float* __restrict__ gin, const float* __restrict__ gk,
        const float4* __restrict__ x,
        int* __restrict__ cnt, int* __restrict__ tok, float* __restrict__ wl,
        uint2* __restrict__ xb) {
    int blk = blockIdx.x;
    int tid = threadIdx.x;

    if (blk < 512) {
        // ---- router ----
        int lane = tid & 63;
        int t = (blk * 256 + tid) >> 6;
        const float* row = gin + (size_t)t * ED;
        float acc[NE];
#pragma unroll
        for (int e = 0; e < NE; e++) acc[e] = 0.f;
        for (int i = lane; i < ED; i += 64) {
            float v = row[i];
            const float* g = gk + i * NE;
#pragma unroll
            for (int e = 0; e < NE; e++) acc[e] = fmaf(v, g[e], acc[e]);
        }
#pragma unroll
        for (int e = 0; e < NE; e++) {
#pragma unroll
            for (int off = 32; off > 0; off >>= 1)
                acc[e] += __shfl_down(acc[e], off, 64);
        }
        if (lane == 0) {
            int b0 = 0; float v0 = acc[0];
#pragma unroll
            for (int e = 1; e < NE; e++) if (acc[e] > v0) { v0 = acc[e]; b0 = e; }
            int b1 = -1; float v1 = -3.4e38f;
#pragma unroll
            for (int e = 0; e < NE; e++) if (e != b0 && acc[e] > v1) { v1 = acc[e]; b1 = e; }
            float w0 = 1.f / (1.f + __expf(-v0));
            float w1 = 1.f / (1.f + __expf(-v1));
            int p0 = atomicAdd(&cnt[b0], 1);
            tok[b0 * NTOK + p0] = t; wl[b0 * NTOK + p0] = w0;
            int p1 = atomicAdd(&cnt[b1], 1);
            tok[b1 * NTOK + p1] = t; wl[b1 * NTOK + p1] = w1;
        }
        return;
    }

    // ---- x -> bf16 ----
    int i = (blk - 512) * 256 + tid;
    float4 v = x[i];
    uint2 o;
    o.x = pk2(v.x, v.y);
    o.y = pk2(v.z, v.w);
    xb[i] = o;
}

// ---------------- pass A: gate+up GEMM from f32 weights, gelu*up ----------
// B staging: thread (n4 = tid&31, k8 = tid>>5) loads 8 f32x4 rows
// (k8*8 + 0..7, cols n4*4..+3) per matrix, packs k-pairs -> bf16, writes
// 4x ds_write_b128 at word (k8, n4*4+j). Transpose+convert fused into
// staging; no weight-image pass.

__global__ __launch_bounds__(256, 2) void k_passA(
        const u16* __restrict__ xb,
        const float* __restrict__ wgf, const float* __restrict__ wuf,
        const int* __restrict__ cnt, const int* __restrict__ off,
        const int* __restrict__ tok, u16* __restrict__ act) {
    int e = blockIdx.z, mt = blockIdx.y, nt = blockIdx.x;
    int c = cnt[e];
    if (mt * BM >= c) return;
    int rmax = c - mt * BM; if (rmax > BM) rmax = BM;

    __shared__ u16 sA[BM * BK];
    __shared__ u16 sBg[BN * BK];
    __shared__ u16 sBu[BN * BK];

    int tid = threadIdx.x;
    int lane = tid & 63, wv = tid >> 6;
    int wm = wv >> 1, wn = wv & 1;
    int col = lane & 15, quad = lane >> 4;
    int swz = col & 7;

    f32x4 zero = {0.f, 0.f, 0.f, 0.f};
    f32x4 ag[4][4], au[4][4];
#pragma unroll
    for (int i = 0; i < 4; i++)
#pragma unroll
        for (int j = 0; j < 4; j++) { ag[i][j] = zero; au[i][j] = zero; }

    // A staging: thread -> (row am, half ah), 32 elems per thread per chunk
    int am = tid >> 1, ah = tid & 1;
    int ridx = mt * BM + am; if (ridx > c - 1) ridx = c - 1;
    int trow = tok[e * NTOK + ridx];
    const u16* asrc = xb + (size_t)trow * ED + ah * 32;
    u16* adst = sA + am * BK;

    // B staging bases (f32 weights, [e][k=1024][n=2048])
    int n4 = tid & 31;            // n-quad
    int k8 = tid >> 5;            // k-oct
    const float* gb = wgf + ((size_t)e * ED + (size_t)k8 * 8) * FD + nt * 128 + n4 * 4;
    const float* ub = wuf + ((size_t)e * ED + (size_t)k8 * 8) * FD + nt * 128 + n4 * 4;
    u16* bgw = sBg + (k8 * 128 + n4 * 4) * 8;
    u16* buw = sBu + (k8 * 128 + n4 * 4) * 8;

    for (int kc = 0; kc < 16; kc++) {
        __syncthreads();
        // issue all 16 weight loads for this K-step
        const float* g0 = gb + (size_t)kc * 64 * FD;
        const float* u0 = ub + (size_t)kc * 64 * FD;
        f32x4 vg[8], vu[8];
#pragma unroll
        for (int r = 0; r < 8; r++) {
            vg[r] = *(const f32x4*)(g0 + (size_t)r * FD);
            vu[r] = *(const f32x4*)(u0 + (size_t)r * FD);
        }
        // sA write in the load shadow
        const u16* as = asrc + kc * 64;
#pragma unroll
        for (int j = 0; j < 4; j++) {
            int pg = (ah * 4 + j) ^ (am & 7);       // sA keeps XOR layout
            *(u32v4*)(adst + pg * 8) = *(const u32v4*)(as + j * 8);
        }
        // convert + pack k-pairs + transposed LDS write
#pragma unroll
        for (int j = 0; j < 4; j++) {
            u32v4 w;
            w.x = pk2(vg[0][j], vg[1][j]);
            w.y = pk2(vg[2][j], vg[3][j]);
            w.z = pk2(vg[4][j], vg[5][j]);
            w.w = pk2(vg[6][j], vg[7][j]);
            *(u32v4*)(bgw + j * 8) = w;
        }
#pragma unroll
        for (int j = 0; j < 4; j++) {
            u32v4 w;
            w.x = pk2(vu[0][j], vu[1][j]);
            w.y = pk2(vu[2][j], vu[3][j]);
            w.z = pk2(vu[4][j], vu[5][j]);
            w.w = pk2(vu[6][j], vu[7][j]);
            *(u32v4*)(buw + j * 8) = w;
        }
        __syncthreads();
#pragma unroll
        for (int st = 0; st < 2; st++) {
            int g4 = st * 4 + quad;
            int aoff = (g4 ^ swz) * 8;               // sA XOR layout
            s16x8 af[4];
#pragma unroll
            for (int mf = 0; mf < 4; mf++)
                af[mf] = *(const s16x8*)(sA + (wm * 64 + mf * 16 + col) * BK + aoff);
#pragma unroll
            for (int nf = 0; nf < 4; nf++) {
                int boff = g4 * 1024 + (wn * 64 + nf * 16 + col) * 8;  // [g][rc]
                s16x8 bg = *(const s16x8*)(sBg + boff);
                s16x8 bu = *(const s16x8*)(sBu + boff);
#pragma unroll
                for (int mf = 0; mf < 4; mf++) {
                    ag[mf][nf] = __builtin_amdgcn_mfma_f32_16x16x32_bf16(af[mf], bg, ag[mf][nf], 0, 0, 0);
                    au[mf][nf] = __builtin_amdgcn_mfma_f32_16x16x32_bf16(af[mf], bu, au[mf][nf], 0, 0, 0);
                }
            }
        }
    }

    // epilogue: act = gelu_tanh(gate) * up, store bf16 into [g][m] act images
    int tile = (off[e] >> 7) + mt;
    u16* ab = act + (size_t)tile * (32 * 8192);
#pragma unroll
    for (int mf = 0; mf < 4; mf++) {
#pragma unroll
        for (int reg = 0; reg < 4; reg++) {
            int m = wm * 64 + mf * 16 + quad * 4 + reg;
            if (m < rmax) {
#pragma unroll
                for (int nf = 0; nf < 4; nf++) {
                    float gv = ag[mf][nf][reg];
                    float uv = au[mf][nf][reg];
                    float z = 0.7978845608028654f * (gv + 0.044715f * gv * gv * gv);
                    float ez = __expf(-2.f * fabsf(z));
                    float th = (1.f - ez) / (1.f + ez);
                    th = (z < 0.f) ? -th : th;
                    float a = 0.5f * gv * (1.f + th) * uv;
                    int ng = nt * 128 + wn * 64 + nf * 16 + col;
                    ab[(size_t)(ng >> 6) * 8192 + (size_t)((ng >> 3) & 7) * 1024
                       + (size_t)m * 8 + (ng & 7)] = f2bf(a);
                }
            }
        }
    }
}

// ---------------- pass B: down GEMM from f32 weights + weighted scatter ----

__global__ __launch_bounds__(256, 3) void k_passB(
        const u16* __restrict__ act, const float* __restrict__ wdf,
        const int* __restrict__ cnt, const int* __restrict__ off,
        const int* __restrict__ tok, const float* __restrict__ wl,
        const float* __restrict__ scale, float* __restrict__ out) {
    int e = blockIdx.z, mt = blockIdx.y, nt = blockIdx.x;
    int c = cnt[e];
    if (mt * BM >= c) return;
    int rmax = c - mt * BM; if (rmax > BM) rmax = BM;

    __shared__ u16 sA[BM * BK];
    __shared__ u16 sB[BN * BK];

    int tid = threadIdx.x;
    int lane = tid & 63, wv = tid >> 6;
    int wm = wv >> 1, wn = wv & 1;
    int col = lane & 15, quad = lane >> 4;

    f32x4 zero = {0.f, 0.f, 0.f, 0.f};
    f32x4 acc[4][4];
#pragma unroll
    for (int i = 0; i < 4; i++)
#pragma unroll
        for (int j = 0; j < 4; j++) acc[i][j] = zero;

    int tile = (off[e] >> 7) + mt;
    const u16* ga = act + (size_t)tile * (32 * 8192);

    // B staging bases (f32 down weights, [e][k=2048][n=1024])
    int n4 = tid & 31;
    int k8 = tid >> 5;
    const float* db = wdf + ((size_t)e * FD + (size_t)k8 * 8) * ED + nt * 128 + n4 * 4;
    u16* bw = sB + (k8 * 128 + n4 * 4) * 8;

    for (int kc = 0; kc < 32; kc++) {
        __syncthreads();
        // A tile (act image, already bf16 in [g][rc] format): async -> LDS
        const u16* as = ga + (size_t)kc * 8192 + wv * 2048 + lane * 8;
        u16* ad = sA + wv * 2048 + lane * 8;
#pragma unroll
        for (int i = 0; i < 4; i++)
            gload16(as + i * 512, ad + i * 512);
        // B tile: f32 loads + convert + transposed LDS write
        const float* d0 = db + (size_t)kc * 64 * ED;
        f32x4 vd[8];
#pragma unroll
        for (int r = 0; r < 8; r++)
            vd[r] = *(const f32x4*)(d0 + (size_t)r * ED);
#pragma unroll
        for (int j = 0; j < 4; j++) {
            u32v4 w;
            w.x = pk2(vd[0][j], vd[1][j]);
            w.y = pk2(vd[2][j], vd[3][j]);
            w.z = pk2(vd[4][j], vd[5][j]);
            w.w = pk2(vd[6][j], vd[7][j]);
            *(u32v4*)(bw + j * 8) = w;
        }
        __syncthreads();
#pragma unroll
        for (int st = 0; st < 2; st++) {
            int g4 = st * 4 + quad;
            int abase = g4 * 1024;                   // [g][rc] layout both sides
            s16x8 af[4];
#pragma unroll
            for (int mf = 0; mf < 4; mf++)
                af[mf] = *(const s16x8*)(sA + abase + (wm * 64 + mf * 16 + col) * 8);
#pragma unroll
            for (int nf = 0; nf < 4; nf++) {
                s16x8 bf = *(const s16x8*)(sB + abase + (wn * 64 + nf * 16 + col) * 8);
#pragma unroll
                for (int mf = 0; mf < 4; mf++)
                    acc[mf][nf] = __builtin_amdgcn_mfma_f32_16x16x32_bf16(af[mf], bf, acc[mf][nf], 0, 0, 0);
            }
        }
    }

    float sc = scale[e];
    int lbase = e * NTOK + mt * BM;
#pragma unroll
    for (int mf = 0; mf < 4; mf++) {
#pragma unroll
        for (int reg = 0; reg < 4; reg++) {
            int m = wm * 64 + mf * 16 + quad * 4 + reg;
            if (m < rmax) {
                int t = tok[lbase + m];
                float w = wl[lbase + m] * sc;
                float* orow = out + (size_t)t * ED + nt * 128 + wn * 64 + col;
#pragma unroll
                for (int nf = 0; nf < 4; nf++)
                    atomicAdd(orow + nf * 16, acc[mf][nf][reg] * w);
            }
        }
    }
}

// ---------------- launch ----------------

extern "C" void kernel_launch(void* const* d_in, const int* in_sizes, int n_in,
                              void* d_out, int out_size, void* d_ws, size_t ws_size,
                              hipStream_t stream) {
    const float* x   = (const float*)d_in[0];
    const float* gin = (const float*)d_in[1];
    const float* gk  = (const float*)d_in[2];
    const float* sc  = (const float*)d_in[3];
    const float* wgf = (const float*)d_in[4];
    const float* wuf = (const float*)d_in[5];
    const float* wdf = (const float*)d_in[6];
    float* out = (float*)d_out;

    if (ws_size < (size_t)WS_NEED) {
        hipMemsetAsync(d_out, 0, (size_t)out_size * sizeof(float), stream);
        return;
    }

    char* ws = (char*)d_ws;
    int*   cnt = (int*)(ws + WS_CNT);
    int*   off = (int*)(ws + WS_OFF);
    int*   tok = (int*)(ws + WS_TOK);
    float* wl  = (float*)(ws + WS_WT);
    u16*   xb  = (u16*)(ws + WS_XB);
    u16*   act = (u16*)(ws + WS_ACT);

    hipMemsetAsync(cnt, 0, 64, stream);
    hipMemsetAsync(d_out, 0, (size_t)out_size * sizeof(float), stream);

    k_prep<<<dim3(2560), dim3(256), 0, stream>>>(gin, gk, (const float4*)x,
                                                 cnt, tok, wl, (uint2*)xb);
    k_scan<<<dim3(1), dim3(64), 0, stream>>>(cnt, off);
    k_passA<<<dim3(16, 16, NE), dim3(256), 0, stream>>>(xb, wgf, wuf,
                                                        cnt, off, tok, act);
    k_passB<<<dim3(8, 16, NE), dim3(256), 0, stream>>>(act, wdf, cnt, off, tok,
                                                       wl, sc, out);
}

// Round 6
// 408.990 us; speedup vs baseline: 1.5671x; 1.5671x over previous
//
#include <hip/hip_runtime.h>
#include <math.h>
#include <stdint.h>

#define NE 8
#define ED 1024
#define FD 2048
#define NTOK 2048
#define BM 128
#define BN 128
#define BK 64

typedef unsigned short u16;
typedef unsigned int u32;
typedef __attribute__((ext_vector_type(4))) float f32x4;
typedef __attribute__((ext_vector_type(8))) short s16x8;
typedef __attribute__((ext_vector_type(4))) unsigned int u32v4;

// ---------------- helpers ----------------

__device__ __forceinline__ u16 f2bf(float f) {
    u32 u = __builtin_bit_cast(u32, f);
    u32 r = u + 0x7fffu + ((u >> 16) & 1u);   // RNE
    return (u16)(r >> 16);
}

__device__ __forceinline__ u32 pk2(float a, float b) {
    return (u32)f2bf(a) | ((u32)f2bf(b) << 16);
}

typedef __attribute__((address_space(1))) const void gvoid_t;
typedef __attribute__((address_space(3))) void lvoid_t;

__device__ __forceinline__ void gload16(const void* g, void* l) {
    // async global->LDS, 16B per lane; LDS dest = uniform base + lane*16
    __builtin_amdgcn_global_load_lds((gvoid_t*)g, (lvoid_t*)l, 16, 0, 0);
}

// Image layout: per (e,nt,kc) image of 8192 u16 = 16KB covering a
// [64 k][128 rc] tile. 16-B word index = g*128 + rc  (g = k-oct 0..7,
// rc = row/col within tile 0..127), elems = 8 consecutive k.
// B/act fragment ds_read bank slot = rc&7 -> balanced, no XOR needed.

// workspace layout (bytes)
#define WS_CNT 0u
#define WS_OFF 64u
#define WS_TOK 256u
#define WS_WT  65792u
#define WS_XB  131328u
#define WS_WG  (8u << 20)
#define WS_WU  41943040u
#define WS_WD  75497472u
#define WS_ACT 109051904u
#define WS_NEED 130023424u

__global__ void k_scan(const int* __restrict__ cnt, int* __restrict__ off) {
    if (threadIdx.x == 0 && blockIdx.x == 0) {
        int a = 0;
#pragma unroll
        for (int e = 0; e < NE; e++) { off[e] = a; a += (cnt[e] + 127) & ~127; }
        off[NE] = a;
    }
}

// ---------------- prep0: router + x->bf16 (NO LDS) ----------------
// blocks [0,512): router (one wave per token); [512,2560): cvtx.
// Split from the cvtw slabs so these latency-bound / tiny blocks don't
// inherit the 33KB LDS allocation (round-4 fused prep ran at 1.37 TB/s).

__global__ __launch_bounds__(256) void k_prep0(
        const float* __restrict__ gin, const float* __restrict__ gk,
        const float4* __restrict__ x,
        int* __restrict__ cnt, int* __restrict__ tok, float* __restrict__ wl,
        uint2* __restrict__ xb) {
    int blk = blockIdx.x;
    int tid = threadIdx.x;

    if (blk < 512) {
        // ---- router ----
        int lane = tid & 63;
        int t = (blk * 256 + tid) >> 6;
        const float* row = gin + (size_t)t * ED;
        float acc[NE];
#pragma unroll
        for (int e = 0; e < NE; e++) acc[e] = 0.f;
        for (int i = lane; i < ED; i += 64) {
            float v = row[i];
            const float* g = gk + i * NE;
#pragma unroll
            for (int e = 0; e < NE; e++) acc[e] = fmaf(v, g[e], acc[e]);
        }
#pragma unroll
        for (int e = 0; e < NE; e++) {
#pragma unroll
            for (int off = 32; off > 0; off >>= 1)
                acc[e] += __shfl_down(acc[e], off, 64);
        }
        if (lane == 0) {
            int b0 = 0; float v0 = acc[0];
#pragma unroll
            for (int e = 1; e < NE; e++) if (acc[e] > v0) { v0 = acc[e]; b0 = e; }
            int b1 = -1; float v1 = -3.4e38f;
#pragma unroll
            for (int e = 0; e < NE; e++) if (e != b0 && acc[e] > v1) { v1 = acc[e]; b1 = e; }
            float w0 = 1.f / (1.f + __expf(-v0));
            float w1 = 1.f / (1.f + __expf(-v1));
            int p0 = atomicAdd(&cnt[b0], 1);
            tok[b0 * NTOK + p0] = t; wl[b0 * NTOK + p0] = w0;
            int p1 = atomicAdd(&cnt[b1], 1);
            tok[b1 * NTOK + p1] = t; wl[b1 * NTOK + p1] = w1;
        }
        return;
    }

    // ---- x -> bf16 ----
    int i = (blk - 512) * 256 + tid;
    float4 v = x[i];
    uint2 o;
    o.x = pk2(v.x, v.y);
    o.y = pk2(v.z, v.w);
    xb[i] = o;
}

// ---------------- gate/up weights f32 -> bf16 image tiles ----------------
// One block = one 8-row slab (32KB contiguous read per row-pair set).
// Writes: per wave 1KB contiguous into disjoint 2KB g-slots.

__global__ __launch_bounds__(256, 4) void k_cvtw_gu(
        const float* __restrict__ wgf, const float* __restrict__ wuf,
        u16* __restrict__ og, u16* __restrict__ ou) {
    int b = blockIdx.x;
    const float* src; u16* dst; int e, s;
    if (b < 1024) { src = wgf; dst = og; e = b >> 7; s = b & 127; }
    else          { int b2 = b - 1024; src = wuf; dst = ou; e = b2 >> 7; s = b2 & 127; }
    int kc = s >> 3, g = s & 7;
    const float* base = src + (size_t)e * (size_t)ED * FD + (size_t)s * 8 * FD;

    __shared__ u32 sl[4 * 2052];
    int tid = threadIdx.x;

    // stage 1: contiguous row-pair reads, pack -> LDS
    for (int kp = 0; kp < 4; kp++) {
        const float* r0 = base + (size_t)(2 * kp) * FD;
#pragma unroll
        for (int ch = 0; ch < 2; ch++) {
            int n4 = ch * 256 + tid;
            float4 f0 = *((const float4*)r0 + n4);
            float4 f1 = *((const float4*)(r0 + FD) + n4);
            u32v4 w;
            w.x = pk2(f0.x, f1.x);
            w.y = pk2(f0.y, f1.y);
            w.z = pk2(f0.z, f1.z);
            w.w = pk2(f0.w, f1.w);
            *(u32v4*)(sl + kp * 2052 + 4 * n4) = w;
        }
    }
    __syncthreads();

    // stage 2: one 16-B word per column n -> image g-slot (contiguous/wave)
#pragma unroll
    for (int it = 0; it < 8; it++) {
        int n = it * 256 + tid;
        u32v4 w;
        w.x = sl[0 * 2052 + n];
        w.y = sl[1 * 2052 + n];
        w.z = sl[2 * 2052 + n];
        w.w = sl[3 * 2052 + n];
        int nt = n >> 7;
        int img = (e * 16 + nt) * 16 + kc;
        u16* ob = dst + (size_t)img * 8192 + (size_t)g * 1024 + (size_t)(n & 127) * 8;
        *(u32v4*)ob = w;
    }
}

// ---------------- pass A: gate+up GEMM + gelu*up + embedded down-convert ----
// z in [0,8): GEMM for expert z. z in [8,16): down-weight f32->bf16 slabs
// (2048 blocks) overlapped with the compute-bound GEMM blocks.

__global__ __launch_bounds__(256, 2) void k_passA(
        const u16* __restrict__ xb, const u16* __restrict__ wg, const u16* __restrict__ wu,
        const float* __restrict__ wdf, u16* __restrict__ od,
        const int* __restrict__ cnt, const int* __restrict__ off,
        const int* __restrict__ tok, u16* __restrict__ act) {
    __shared__ __align__(16) u16 smem[3 * 8192];
    int tid = threadIdx.x;

    if (blockIdx.z >= 8) {
        // ---- down-weight convert: one block = one 8-row slab of [FD][ED] ----
        int cid = (int)((blockIdx.z - 8) * 256 + blockIdx.y * 16 + blockIdx.x);
        int e = cid >> 8, s = cid & 255;
        int kc = s >> 3, g = s & 7;
        const float* base = wdf + (size_t)e * (size_t)FD * ED + (size_t)s * 8 * ED;
        u32* sl = (u32*)smem;          // 4*1028 u32 = 16.4 KB
        for (int kp = 0; kp < 4; kp++) {
            const float* r0 = base + (size_t)(2 * kp) * ED;
            int n4 = tid;              // 256 float4 per 1024-float row
            float4 f0 = *((const float4*)r0 + n4);
            float4 f1 = *((const float4*)(r0 + ED) + n4);
            u32v4 w;
            w.x = pk2(f0.x, f1.x);
            w.y = pk2(f0.y, f1.y);
            w.z = pk2(f0.z, f1.z);
            w.w = pk2(f0.w, f1.w);
            *(u32v4*)(sl + kp * 1028 + 4 * n4) = w;
        }
        __syncthreads();
#pragma unroll
        for (int it = 0; it < 4; it++) {
            int n = it * 256 + tid;
            u32v4 w;
            w.x = sl[0 * 1028 + n];
            w.y = sl[1 * 1028 + n];
            w.z = sl[2 * 1028 + n];
            w.w = sl[3 * 1028 + n];
            int nt = n >> 7;
            int img = (e * 8 + nt) * 32 + kc;
            *(u32v4*)(od + (size_t)img * 8192 + (size_t)g * 1024 + (size_t)(n & 127) * 8) = w;
        }
        return;
    }

    int e = blockIdx.z, mt = blockIdx.y, nt = blockIdx.x;
    int c = cnt[e];
    if (mt * BM >= c) return;
    int rmax = c - mt * BM; if (rmax > BM) rmax = BM;

    u16* sA  = smem;
    u16* sBg = smem + 8192;
    u16* sBu = smem + 16384;

    int lane = tid & 63, wv = tid >> 6;
    int wm = wv >> 1, wn = wv & 1;
    int col = lane & 15, quad = lane >> 4;
    int swz = col & 7;

    f32x4 zero = {0.f, 0.f, 0.f, 0.f};
    f32x4 ag[4][4], au[4][4];
#pragma unroll
    for (int i = 0; i < 4; i++)
#pragma unroll
        for (int j = 0; j < 4; j++) { ag[i][j] = zero; au[i][j] = zero; }

    // A staging: thread -> (row am, half ah), 32 elems per thread per chunk
    int am = tid >> 1, ah = tid & 1;
    int ridx = mt * BM + am; if (ridx > c - 1) ridx = c - 1;
    int trow = tok[e * NTOK + ridx];
    const u16* asrc = xb + (size_t)trow * ED + ah * 32;
    u16* adst = sA + am * BK;

    const u16* gg = wg + ((size_t)(e * 16 + nt) * 16) * 8192;
    const u16* gu = wu + ((size_t)(e * 16 + nt) * 16) * 8192;
    const u16* bsrc0 = (wv < 2 ? gg : gu);
    int bhalf = (wv & 1) * 4096;
    u16* bdst = (wv < 2 ? sBg : sBu) + bhalf;

    for (int kc = 0; kc < 16; kc++) {
        __syncthreads();
        const u16* bs = bsrc0 + (size_t)kc * 8192 + bhalf + lane * 8;
#pragma unroll
        for (int i = 0; i < 8; i++)
            gload16(bs + i * 512, bdst + i * 512);
        const u16* as = asrc + kc * 64;
#pragma unroll
        for (int j = 0; j < 4; j++) {
            int pg = (ah * 4 + j) ^ (am & 7);       // sA keeps XOR layout
            *(u32v4*)(adst + pg * 8) = *(const u32v4*)(as + j * 8);
        }
        __syncthreads();
#pragma unroll
        for (int st = 0; st < 2; st++) {
            int g4 = st * 4 + quad;
            int aoff = (g4 ^ swz) * 8;               // sA XOR layout
            s16x8 af[4];
#pragma unroll
            for (int mf = 0; mf < 4; mf++)
                af[mf] = *(const s16x8*)(sA + (wm * 64 + mf * 16 + col) * BK + aoff);
#pragma unroll
            for (int nf = 0; nf < 4; nf++) {
                int boff = g4 * 1024 + (wn * 64 + nf * 16 + col) * 8;  // [g][rc]
                s16x8 bg = *(const s16x8*)(sBg + boff);
                s16x8 bu = *(const s16x8*)(sBu + boff);
#pragma unroll
                for (int mf = 0; mf < 4; mf++) {
                    ag[mf][nf] = __builtin_amdgcn_mfma_f32_16x16x32_bf16(af[mf], bg, ag[mf][nf], 0, 0, 0);
                    au[mf][nf] = __builtin_amdgcn_mfma_f32_16x16x32_bf16(af[mf], bu, au[mf][nf], 0, 0, 0);
                }
            }
        }
    }

    // epilogue: act = gelu_tanh(gate) * up, store bf16 into [g][m] act images
    int tile = (off[e] >> 7) + mt;
    u16* ab = act + (size_t)tile * (32 * 8192);
#pragma unroll
    for (int mf = 0; mf < 4; mf++) {
#pragma unroll
        for (int reg = 0; reg < 4; reg++) {
            int m = wm * 64 + mf * 16 + quad * 4 + reg;
            if (m < rmax) {
#pragma unroll
                for (int nf = 0; nf < 4; nf++) {
                    float gv = ag[mf][nf][reg];
                    float uv = au[mf][nf][reg];
                    float z = 0.7978845608028654f * (gv + 0.044715f * gv * gv * gv);
                    float ez = __expf(-2.f * fabsf(z));
                    float th = (1.f - ez) / (1.f + ez);
                    th = (z < 0.f) ? -th : th;
                    float a = 0.5f * gv * (1.f + th) * uv;
                    int ng = nt * 128 + wn * 64 + nf * 16 + col;
                    ab[(size_t)(ng >> 6) * 8192 + (size_t)((ng >> 3) & 7) * 1024
                       + (size_t)m * 8 + (ng & 7)] = f2bf(a);
                }
            }
        }
    }
}

// ---------------- pass B: down GEMM + weighted scatter ----------------

__global__ __launch_bounds__(256, 3) void k_passB(
        const u16* __restrict__ act, const u16* __restrict__ wd,
        const int* __restrict__ cnt, const int* __restrict__ off,
        const int* __restrict__ tok, const float* __restrict__ wl,
        const float* __restrict__ scale, float* __restrict__ out) {
    int e = blockIdx.z, mt = blockIdx.y, nt = blockIdx.x;
    int c = cnt[e];
    if (mt * BM >= c) return;
    int rmax = c - mt * BM; if (rmax > BM) rmax = BM;

    __shared__ u16 sA[BM * BK];
    __shared__ u16 sB[BN * BK];

    int tid = threadIdx.x;
    int lane = tid & 63, wv = tid >> 6;
    int wm = wv >> 1, wn = wv & 1;
    int col = lane & 15, quad = lane >> 4;

    f32x4 zero = {0.f, 0.f, 0.f, 0.f};
    f32x4 acc[4][4];
#pragma unroll
    for (int i = 0; i < 4; i++)
#pragma unroll
        for (int j = 0; j < 4; j++) acc[i][j] = zero;

    int tile = (off[e] >> 7) + mt;
    const u16* ga = act + (size_t)tile * (32 * 8192);
    const u16* gb = wd + ((size_t)(e * 8 + nt) * 32) * 8192;
    const u16* src0 = (wv < 2 ? ga : gb);
    int shalf = (wv & 1) * 4096;
    u16* dst0 = (wv < 2 ? sA : sB) + shalf;

    for (int kc = 0; kc < 32; kc++) {
        __syncthreads();
        const u16* s = src0 + (size_t)kc * 8192 + shalf + lane * 8;
#pragma unroll
        for (int i = 0; i < 8; i++)
            gload16(s + i * 512, dst0 + i * 512);
        __syncthreads();
#pragma unroll
        for (int st = 0; st < 2; st++) {
            int g4 = st * 4 + quad;
            int abase = g4 * 1024;                   // [g][rc] layout both sides
            s16x8 af[4];
#pragma unroll
            for (int mf = 0; mf < 4; mf++)
                af[mf] = *(const s16x8*)(sA + abase + (wm * 64 + mf * 16 + col) * 8);
#pragma unroll
            for (int nf = 0; nf < 4; nf++) {
                s16x8 bf = *(const s16x8*)(sB + abase + (wn * 64 + nf * 16 + col) * 8);
#pragma unroll
                for (int mf = 0; mf < 4; mf++)
                    acc[mf][nf] = __builtin_amdgcn_mfma_f32_16x16x32_bf16(af[mf], bf, acc[mf][nf], 0, 0, 0);
            }
        }
    }

    float sc = scale[e];
    int lbase = e * NTOK + mt * BM;
#pragma unroll
    for (int mf = 0; mf < 4; mf++) {
#pragma unroll
        for (int reg = 0; reg < 4; reg++) {
            int m = wm * 64 + mf * 16 + quad * 4 + reg;
            if (m < rmax) {
                int t = tok[lbase + m];
                float w = wl[lbase + m] * sc;
                float* orow = out + (size_t)t * ED + nt * 128 + wn * 64 + col;
#pragma unroll
                for (int nf = 0; nf < 4; nf++)
                    atomicAdd(orow + nf * 16, acc[mf][nf][reg] * w);
            }
        }
    }
}

// ---------------- launch ----------------

extern "C" void kernel_launch(void* const* d_in, const int* in_sizes, int n_in,
                              void* d_out, int out_size, void* d_ws, size_t ws_size,
                              hipStream_t stream) {
    const float* x   = (const float*)d_in[0];
    const float* gin = (const float*)d_in[1];
    const float* gk  = (const float*)d_in[2];
    const float* sc  = (const float*)d_in[3];
    const float* wgf = (const float*)d_in[4];
    const float* wuf = (const float*)d_in[5];
    const float* wdf = (const float*)d_in[6];
    float* out = (float*)d_out;

    if (ws_size < (size_t)WS_NEED) {
        hipMemsetAsync(d_out, 0, (size_t)out_size * sizeof(float), stream);
        return;
    }

    char* ws = (char*)d_ws;
    int*   cnt = (int*)(ws + WS_CNT);
    int*   off = (int*)(ws + WS_OFF);
    int*   tok = (int*)(ws + WS_TOK);
    float* wl  = (float*)(ws + WS_WT);
    u16*   xb  = (u16*)(ws + WS_XB);
    u16*   og  = (u16*)(ws + WS_WG);
    u16*   ou  = (u16*)(ws + WS_WU);
    u16*   od  = (u16*)(ws + WS_WD);
    u16*   act = (u16*)(ws + WS_ACT);

    hipMemsetAsync(cnt, 0, 64, stream);
    hipMemsetAsync(d_out, 0, (size_t)out_size * sizeof(float), stream);

    k_prep0<<<dim3(2560), dim3(256), 0, stream>>>(gin, gk, (const float4*)x,
                                                  cnt, tok, wl, (uint2*)xb);
    k_cvtw_gu<<<dim3(2048), dim3(256), 0, stream>>>(wgf, wuf, og, ou);
    k_scan<<<dim3(1), dim3(64), 0, stream>>>(cnt, off);
    k_passA<<<dim3(16, 16, 16), dim3(256), 0, stream>>>(xb, og, ou, wdf, od,
                                                        cnt, off, tok, act);
    k_passB<<<dim3(8, 16, NE), dim3(256), 0, stream>>>(act, od, cnt, off, tok,
                                                       wl, sc, out);
}

// Round 7
// 375.764 us; speedup vs baseline: 1.7056x; 1.0884x over previous
//
#include <hip/hip_runtime.h>
#include <math.h>
#include <stdint.h>

#define NE 8
#define ED 1024
#define FD 2048
#define NTOK 2048
#define BM 128
#define BN 128
#define BK 64

typedef unsigned short u16;
typedef unsigned int u32;
typedef __attribute__((ext_vector_type(4))) float f32x4;
typedef __attribute__((ext_vector_type(8))) short s16x8;
typedef __attribute__((ext_vector_type(4))) unsigned int u32v4;

// ---------------- helpers ----------------

__device__ __forceinline__ u16 f2bf(float f) {
    u32 u = __builtin_bit_cast(u32, f);
    u32 r = u + 0x7fffu + ((u >> 16) & 1u);   // RNE
    return (u16)(r >> 16);
}

__device__ __forceinline__ u32 pk2(float a, float b) {
    return (u32)f2bf(a) | ((u32)f2bf(b) << 16);
}

typedef __attribute__((address_space(1))) const void gvoid_t;
typedef __attribute__((address_space(3))) void lvoid_t;

__device__ __forceinline__ void gload16(const void* g, void* l) {
    // async global->LDS, 16B per lane; LDS dest = uniform base + lane*16
    __builtin_amdgcn_global_load_lds((gvoid_t*)g, (lvoid_t*)l, 16, 0, 0);
}

// per-block expert offset scan (replaces k_scan dispatch): off[e] =
// sum of 128-padded counts of experts < e.
__device__ __forceinline__ int exp_off(const int* cnt, int e) {
    int a = 0;
    for (int i = 0; i < e; i++) a += (cnt[i] + 127) & ~127;
    return a;
}

// Image layout: per (e,nt,kc) image of 8192 u16 = 16KB covering a
// [64 k][128 rc] tile. 16-B word index = g*128 + rc  (g = k-oct 0..7,
// rc = row/col within tile 0..127), elems = 8 consecutive k.
// B/act fragment ds_read bank slot = rc&7 -> balanced, no XOR needed.

// workspace layout (bytes)
#define WS_CNT 0u
#define WS_OFF 64u
#define WS_TOK 256u
#define WS_WT  65792u
#define WS_XB  131328u
#define WS_WG  (8u << 20)
#define WS_WU  41943040u
#define WS_WD  75497472u
#define WS_ACT 109051904u
#define WS_NEED 130023424u

// ---------------- fused prep ----------------
// blocks [0,2048):    gate/up weight f32->bf16 image slabs (long, FIRST)
// blocks [2048,2560): router (one wave per token)
// blocks [2560,4608): x -> bf16
// blocks [4608,5120): zero d_out (replaces hipMemsetAsync dispatch)

__global__ __launch_bounds__(256, 4) void k_prep(
        const float* __restrict__ gin, const float* __restrict__ gk,
        const float4* __restrict__ x,
        const float* __restrict__ wgf, const float* __restrict__ wuf,
        int* __restrict__ cnt, int* __restrict__ tok, float* __restrict__ wl,
        uint2* __restrict__ xb, u16* __restrict__ og, u16* __restrict__ ou,
        float4* __restrict__ outz) {
    __shared__ u32 sl[4 * 2052];
    int blk = blockIdx.x;
    int tid = threadIdx.x;

    if (blk < 2048) {
        // ---- gate/up convert: one block = one 8-row slab ----
        const float* src; u16* dst; int e, s;
        if (blk < 1024) { src = wgf; dst = og; e = blk >> 7; s = blk & 127; }
        else            { int b2 = blk - 1024; src = wuf; dst = ou; e = b2 >> 7; s = b2 & 127; }
        int kc = s >> 3, g = s & 7;
        const float* base = src + (size_t)e * (size_t)ED * FD + (size_t)s * 8 * FD;

        // stage 1: contiguous row-pair reads, pack -> LDS
        for (int kp = 0; kp < 4; kp++) {
            const float* r0 = base + (size_t)(2 * kp) * FD;
#pragma unroll
            for (int ch = 0; ch < 2; ch++) {
                int n4 = ch * 256 + tid;
                float4 f0 = *((const float4*)r0 + n4);
                float4 f1 = *((const float4*)(r0 + FD) + n4);
                u32v4 w;
                w.x = pk2(f0.x, f1.x);
                w.y = pk2(f0.y, f1.y);
                w.z = pk2(f0.z, f1.z);
                w.w = pk2(f0.w, f1.w);
                *(u32v4*)(sl + kp * 2052 + 4 * n4) = w;
            }
        }
        __syncthreads();

        // stage 2: one 16-B word per column n -> image g-slot
#pragma unroll
        for (int it = 0; it < 8; it++) {
            int n = it * 256 + tid;
            u32v4 w;
            w.x = sl[0 * 2052 + n];
            w.y = sl[1 * 2052 + n];
            w.z = sl[2 * 2052 + n];
            w.w = sl[3 * 2052 + n];
            int nt = n >> 7;
            int img = (e * 16 + nt) * 16 + kc;
            u16* ob = dst + (size_t)img * 8192 + (size_t)g * 1024 + (size_t)(n & 127) * 8;
            *(u32v4*)ob = w;
        }
        return;
    }

    if (blk < 2560) {
        // ---- router ----
        int lane = tid & 63;
        int t = ((blk - 2048) * 256 + tid) >> 6;
        const float* row = gin + (size_t)t * ED;
        float acc[NE];
#pragma unroll
        for (int e = 0; e < NE; e++) acc[e] = 0.f;
        for (int i = lane; i < ED; i += 64) {
            float v = row[i];
            const float* g = gk + i * NE;
#pragma unroll
            for (int e = 0; e < NE; e++) acc[e] = fmaf(v, g[e], acc[e]);
        }
#pragma unroll
        for (int e = 0; e < NE; e++) {
#pragma unroll
            for (int off = 32; off > 0; off >>= 1)
                acc[e] += __shfl_down(acc[e], off, 64);
        }
        if (lane == 0) {
            int b0 = 0; float v0 = acc[0];
#pragma unroll
            for (int e = 1; e < NE; e++) if (acc[e] > v0) { v0 = acc[e]; b0 = e; }
            int b1 = -1; float v1 = -3.4e38f;
#pragma unroll
            for (int e = 0; e < NE; e++) if (e != b0 && acc[e] > v1) { v1 = acc[e]; b1 = e; }
            float w0 = 1.f / (1.f + __expf(-v0));
            float w1 = 1.f / (1.f + __expf(-v1));
            int p0 = atomicAdd(&cnt[b0], 1);
            tok[b0 * NTOK + p0] = t; wl[b0 * NTOK + p0] = w0;
            int p1 = atomicAdd(&cnt[b1], 1);
            tok[b1 * NTOK + p1] = t; wl[b1 * NTOK + p1] = w1;
        }
        return;
    }

    if (blk < 4608) {
        // ---- x -> bf16 ----
        int i = (blk - 2560) * 256 + tid;
        float4 v = x[i];
        uint2 o;
        o.x = pk2(v.x, v.y);
        o.y = pk2(v.z, v.w);
        xb[i] = o;
        return;
    }

    // ---- zero d_out (2M floats = 512 blocks * 256 threads * float4) ----
    {
        int i = (blk - 4608) * 256 + tid;
        outz[i] = (float4){0.f, 0.f, 0.f, 0.f};
    }
}

// ---------------- pass A: gate+up GEMM + gelu*up + embedded down-convert ----
// z in [0,8): GEMM for expert z. z in [8,16): down-weight f32->bf16 slabs
// (2048 blocks) overlapped with the compute-bound GEMM blocks.

__global__ __launch_bounds__(256, 3) void k_passA(
        const u16* __restrict__ xb, const u16* __restrict__ wg, const u16* __restrict__ wu,
        const float* __restrict__ wdf, u16* __restrict__ od,
        const int* __restrict__ cnt,
        const int* __restrict__ tok, u16* __restrict__ act) {
    __shared__ __align__(16) u16 smem[3 * 8192];
    int tid = threadIdx.x;

    if (blockIdx.z >= 8) {
        // ---- down-weight convert: one block = one 8-row slab of [FD][ED] ----
        int cid = (int)((blockIdx.z - 8) * 256 + blockIdx.y * 16 + blockIdx.x);
        int e = cid >> 8, s = cid & 255;
        int kc = s >> 3, g = s & 7;
        const float* base = wdf + (size_t)e * (size_t)FD * ED + (size_t)s * 8 * ED;
        u32* sl = (u32*)smem;          // 4*1028 u32 = 16.4 KB
        for (int kp = 0; kp < 4; kp++) {
            const float* r0 = base + (size_t)(2 * kp) * ED;
            int n4 = tid;              // 256 float4 per 1024-float row
            float4 f0 = *((const float4*)r0 + n4);
            float4 f1 = *((const float4*)(r0 + ED) + n4);
            u32v4 w;
            w.x = pk2(f0.x, f1.x);
            w.y = pk2(f0.y, f1.y);
            w.z = pk2(f0.z, f1.z);
            w.w = pk2(f0.w, f1.w);
            *(u32v4*)(sl + kp * 1028 + 4 * n4) = w;
        }
        __syncthreads();
#pragma unroll
        for (int it = 0; it < 4; it++) {
            int n = it * 256 + tid;
            u32v4 w;
            w.x = sl[0 * 1028 + n];
            w.y = sl[1 * 1028 + n];
            w.z = sl[2 * 1028 + n];
            w.w = sl[3 * 1028 + n];
            int nt = n >> 7;
            int img = (e * 8 + nt) * 32 + kc;
            *(u32v4*)(od + (size_t)img * 8192 + (size_t)g * 1024 + (size_t)(n & 127) * 8) = w;
        }
        return;
    }

    int e = blockIdx.z, mt = blockIdx.y, nt = blockIdx.x;
    int c = cnt[e];
    if (mt * BM >= c) return;
    int rmax = c - mt * BM; if (rmax > BM) rmax = BM;

    u16* sA  = smem;
    u16* sBg = smem + 8192;
    u16* sBu = smem + 16384;

    int lane = tid & 63, wv = tid >> 6;
    int wm = wv >> 1, wn = wv & 1;
    int col = lane & 15, quad = lane >> 4;
    int swz = col & 7;

    f32x4 zero = {0.f, 0.f, 0.f, 0.f};
    f32x4 ag[4][4], au[4][4];
#pragma unroll
    for (int i = 0; i < 4; i++)
#pragma unroll
        for (int j = 0; j < 4; j++) { ag[i][j] = zero; au[i][j] = zero; }

    // A staging: thread -> (row am, half ah), 32 elems per thread per chunk
    int am = tid >> 1, ah = tid & 1;
    int ridx = mt * BM + am; if (ridx > c - 1) ridx = c - 1;
    int trow = tok[e * NTOK + ridx];
    const u16* asrc = xb + (size_t)trow * ED + ah * 32;
    u16* adst = sA + am * BK;

    const u16* gg = wg + ((size_t)(e * 16 + nt) * 16) * 8192;
    const u16* gu = wu + ((size_t)(e * 16 + nt) * 16) * 8192;
    const u16* bsrc0 = (wv < 2 ? gg : gu);
    int bhalf = (wv & 1) * 4096;
    u16* bdst = (wv < 2 ? sBg : sBu) + bhalf;

    for (int kc = 0; kc < 16; kc++) {
        __syncthreads();
        const u16* bs = bsrc0 + (size_t)kc * 8192 + bhalf + lane * 8;
#pragma unroll
        for (int i = 0; i < 8; i++)
            gload16(bs + i * 512, bdst + i * 512);
        const u16* as = asrc + kc * 64;
#pragma unroll
        for (int j = 0; j < 4; j++) {
            int pg = (ah * 4 + j) ^ (am & 7);       // sA keeps XOR layout
            *(u32v4*)(adst + pg * 8) = *(const u32v4*)(as + j * 8);
        }
        __syncthreads();
#pragma unroll
        for (int st = 0; st < 2; st++) {
            int g4 = st * 4 + quad;
            int aoff = (g4 ^ swz) * 8;               // sA XOR layout
            s16x8 af[4];
#pragma unroll
            for (int mf = 0; mf < 4; mf++)
                af[mf] = *(const s16x8*)(sA + (wm * 64 + mf * 16 + col) * BK + aoff);
#pragma unroll
            for (int nf = 0; nf < 4; nf++) {
                int boff = g4 * 1024 + (wn * 64 + nf * 16 + col) * 8;  // [g][rc]
                s16x8 bg = *(const s16x8*)(sBg + boff);
                s16x8 bu = *(const s16x8*)(sBu + boff);
#pragma unroll
                for (int mf = 0; mf < 4; mf++) {
                    ag[mf][nf] = __builtin_amdgcn_mfma_f32_16x16x32_bf16(af[mf], bg, ag[mf][nf], 0, 0, 0);
                    au[mf][nf] = __builtin_amdgcn_mfma_f32_16x16x32_bf16(af[mf], bu, au[mf][nf], 0, 0, 0);
                }
            }
        }
    }

    // epilogue: act = gelu_tanh(gate) * up, store bf16 into [g][m] act images
    int tile = (exp_off(cnt, e) >> 7) + mt;
    u16* ab = act + (size_t)tile * (32 * 8192);
#pragma unroll
    for (int mf = 0; mf < 4; mf++) {
#pragma unroll
        for (int reg = 0; reg < 4; reg++) {
            int m = wm * 64 + mf * 16 + quad * 4 + reg;
            if (m < rmax) {
#pragma unroll
                for (int nf = 0; nf < 4; nf++) {
                    float gv = ag[mf][nf][reg];
                    float uv = au[mf][nf][reg];
                    float z = 0.7978845608028654f * (gv + 0.044715f * gv * gv * gv);
                    float ez = __expf(-2.f * fabsf(z));
                    float th = (1.f - ez) / (1.f + ez);
                    th = (z < 0.f) ? -th : th;
                    float a = 0.5f * gv * (1.f + th) * uv;
                    int ng = nt * 128 + wn * 64 + nf * 16 + col;
                    ab[(size_t)(ng >> 6) * 8192 + (size_t)((ng >> 3) & 7) * 1024
                       + (size_t)m * 8 + (ng & 7)] = f2bf(a);
                }
            }
        }
    }
}

// ---------------- pass B: down GEMM + weighted scatter ----------------

__global__ __launch_bounds__(256, 4) void k_passB(
        const u16* __restrict__ act, const u16* __restrict__ wd,
        const int* __restrict__ cnt,
        const int* __restrict__ tok, const float* __restrict__ wl,
        const float* __restrict__ scale, float* __restrict__ out) {
    int e = blockIdx.z, mt = blockIdx.y, nt = blockIdx.x;
    int c = cnt[e];
    if (mt * BM >= c) return;
    int rmax = c - mt * BM; if (rmax > BM) rmax = BM;

    __shared__ u16 sA[BM * BK];
    __shared__ u16 sB[BN * BK];

    int tid = threadIdx.x;
    int lane = tid & 63, wv = tid >> 6;
    int wm = wv >> 1, wn = wv & 1;
    int col = lane & 15, quad = lane >> 4;

    f32x4 zero = {0.f, 0.f, 0.f, 0.f};
    f32x4 acc[4][4];
#pragma unroll
    for (int i = 0; i < 4; i++)
#pragma unroll
        for (int j = 0; j < 4; j++) acc[i][j] = zero;

    int tile = (exp_off(cnt, e) >> 7) + mt;
    const u16* ga = act + (size_t)tile * (32 * 8192);
    const u16* gb = wd + ((size_t)(e * 8 + nt) * 32) * 8192;
    const u16* src0 = (wv < 2 ? ga : gb);
    int shalf = (wv & 1) * 4096;
    u16* dst0 = (wv < 2 ? sA : sB) + shalf;

    for (int kc = 0; kc < 32; kc++) {
        __syncthreads();
        const u16* s = src0 + (size_t)kc * 8192 + shalf + lane * 8;
#pragma unroll
        for (int i = 0; i < 8; i++)
            gload16(s + i * 512, dst0 + i * 512);
        __syncthreads();
#pragma unroll
        for (int st = 0; st < 2; st++) {
            int g4 = st * 4 + quad;
            int abase = g4 * 1024;                   // [g][rc] layout both sides
            s16x8 af[4];
#pragma unroll
            for (int mf = 0; mf < 4; mf++)
                af[mf] = *(const s16x8*)(sA + abase + (wm * 64 + mf * 16 + col) * 8);
#pragma unroll
            for (int nf = 0; nf < 4; nf++) {
                s16x8 bf = *(const s16x8*)(sB + abase + (wn * 64 + nf * 16 + col) * 8);
#pragma unroll
                for (int mf = 0; mf < 4; mf++)
                    acc[mf][nf] = __builtin_amdgcn_mfma_f32_16x16x32_bf16(af[mf], bf, acc[mf][nf], 0, 0, 0);
            }
        }
    }

    float sc = scale[e];
    int lbase = e * NTOK + mt * BM;
#pragma unroll
    for (int mf = 0; mf < 4; mf++) {
#pragma unroll
        for (int reg = 0; reg < 4; reg++) {
            int m = wm * 64 + mf * 16 + quad * 4 + reg;
            if (m < rmax) {
                int t = tok[lbase + m];
                float w = wl[lbase + m] * sc;
                float* orow = out + (size_t)t * ED + nt * 128 + wn * 64 + col;
#pragma unroll
                for (int nf = 0; nf < 4; nf++)
                    atomicAdd(orow + nf * 16, acc[mf][nf][reg] * w);
            }
        }
    }
}

// ---------------- launch ----------------

extern "C" void kernel_launch(void* const* d_in, const int* in_sizes, int n_in,
                              void* d_out, int out_size, void* d_ws, size_t ws_size,
                              hipStream_t stream) {
    const float* x   = (const float*)d_in[0];
    const float* gin = (const float*)d_in[1];
    const float* gk  = (const float*)d_in[2];
    const float* sc  = (const float*)d_in[3];
    const float* wgf = (const float*)d_in[4];
    const float* wuf = (const float*)d_in[5];
    const float* wdf = (const float*)d_in[6];
    float* out = (float*)d_out;

    if (ws_size < (size_t)WS_NEED) {
        hipMemsetAsync(d_out, 0, (size_t)out_size * sizeof(float), stream);
        return;
    }

    char* ws = (char*)d_ws;
    int*   cnt = (int*)(ws + WS_CNT);
    int*   tok = (int*)(ws + WS_TOK);
    float* wl  = (float*)(ws + WS_WT);
    u16*   xb  = (u16*)(ws + WS_XB);
    u16*   og  = (u16*)(ws + WS_WG);
    u16*   ou  = (u16*)(ws + WS_WU);
    u16*   od  = (u16*)(ws + WS_WD);
    u16*   act = (u16*)(ws + WS_ACT);

    hipMemsetAsync(cnt, 0, 64, stream);

    k_prep<<<dim3(5120), dim3(256), 0, stream>>>(gin, gk, (const float4*)x,
                                                 wgf, wuf, cnt, tok, wl,
                                                 (uint2*)xb, og, ou, (float4*)out);
    k_passA<<<dim3(16, 16, 16), dim3(256), 0, stream>>>(xb, og, ou, wdf, od,
                                                        cnt, tok, act);
    k_passB<<<dim3(8, 16, NE), dim3(256), 0, stream>>>(act, od, cnt, tok,
                                                       wl, sc, out);
}